// Round 1
// baseline (190.244 us; speedup 1.0000x reference)
//
#include <hip/hip_runtime.h>
#include <math.h>

__device__ __forceinline__ float dot4(float4 a, float4 b){
    return a.x*b.x + a.y*b.y + a.z*b.z + a.w*b.w;
}

// ---------------------------------------------------------------------------
// Kernel 1: AvgPool3d 16^3 : x (64,128,128,128) f32 -> seq (64*512) f32
// One wave per (c, od, oh). Wave reads 256 rows of 128 floats (512B each),
// 2 rows per iteration -> 1KB fully-coalesced per load instruction.
// Each lane's float4 column index f is constant -> single scalar accumulator,
// ow = f>>2 constant per lane. Reduce: xor1, xor2 (4-lane groups), xor32.
// ---------------------------------------------------------------------------
__global__ __launch_bounds__(256) void pool_k(const float* __restrict__ x,
                                              float* __restrict__ seq){
    int tid  = threadIdx.x;
    int lane = tid & 63;
    int wid  = blockIdx.x * 4 + (tid >> 6);   // 0..4095
    int c  = wid >> 6;
    int od = (wid >> 3) & 7;
    int oh = wid & 7;
    int half = lane >> 5;    // which of 2 rows this iteration
    int f    = lane & 31;    // float4 index within 128-float row

    const float4* px = (const float4*)x;
    // float4 units: row stride = 32, h-dim stride = 32, d-dim stride = 128*32 = 4096
    size_t base = ((size_t)(c * 128 + od * 16) * 128 + (size_t)(oh * 16 + half)) * 32 + f;

    float acc = 0.f;
    for (int i = 0; i < 16; i++){
        size_t o = base + (size_t)i * 4096;
        #pragma unroll
        for (int jj = 0; jj < 8; jj++){
            float4 v = px[o + (size_t)jj * 64];   // j = jj*2 + half
            acc += (v.x + v.y) + (v.z + v.w);
        }
    }
    acc += __shfl_xor(acc, 1);
    acc += __shfl_xor(acc, 2);
    acc += __shfl_xor(acc, 32);
    if (lane < 32 && (lane & 3) == 0){
        int ow = lane >> 2;                       // 0..7
        seq[c * 512 + od * 64 + oh * 8 + ow] = acc * (1.0f / 4096.0f);
    }
}

// ---------------------------------------------------------------------------
// Kernel 2: in_proj  xz[l,e] = dot(seq[l,:512], Win[e,:512])   (64 x 2048)
// One wave per output; coalesced float4 reads; 6-step shuffle reduce.
// ---------------------------------------------------------------------------
__global__ __launch_bounds__(256) void inproj_k(const float* __restrict__ seq,
                                                const float* __restrict__ Win,
                                                float* __restrict__ xz){
    int lane = threadIdx.x & 63;
    int wid  = blockIdx.x * 4 + (threadIdx.x >> 6);  // 0..131071
    int l = wid >> 11;
    int e = wid & 2047;
    const float4* S = (const float4*)(seq) + (size_t)l * 128;
    const float4* W = (const float4*)(Win) + (size_t)e * 128;
    float acc = dot4(S[lane], W[lane]) + dot4(S[lane + 64], W[lane + 64]);
    #pragma unroll
    for (int m = 1; m < 64; m <<= 1) acc += __shfl_xor(acc, m);
    if (lane == 0) xz[l * 2048 + e] = acc;
}

// ---------------------------------------------------------------------------
// Kernel 3: causal depthwise conv1d (K=4) along L + bias + SiLU -> xs (64x1024)
// ---------------------------------------------------------------------------
__global__ __launch_bounds__(256) void conv_k(const float* __restrict__ xz,
                                              const float* __restrict__ cw,
                                              const float* __restrict__ cb,
                                              float* __restrict__ xs){
    int idx = blockIdx.x * 256 + threadIdx.x;   // 0..65535
    int l = idx >> 10;
    int e = idx & 1023;
    float v = cb[e];
    #pragma unroll
    for (int t = 0; t < 4; t++){
        int ll = l - 3 + t;
        if (ll >= 0) v += cw[e * 4 + t] * xz[ll * 2048 + e];
    }
    v = v / (1.f + expf(-v));   // SiLU
    xs[l * 1024 + e] = v;
}

// ---------------------------------------------------------------------------
// Kernel 4: x_proj  x_dbl[l,f] = dot(xs[l,:1024], Wx[f,:1024])  (64 x 64)
// ---------------------------------------------------------------------------
__global__ __launch_bounds__(256) void xproj_k(const float* __restrict__ xs,
                                               const float* __restrict__ Wx,
                                               float* __restrict__ xdbl){
    int lane = threadIdx.x & 63;
    int wid  = blockIdx.x * 4 + (threadIdx.x >> 6);  // 0..4095
    int l = wid >> 6;
    int f = wid & 63;
    const float4* X = (const float4*)(xs) + (size_t)l * 256;
    const float4* W = (const float4*)(Wx) + (size_t)f * 256;
    float acc = 0.f;
    #pragma unroll
    for (int q = 0; q < 4; q++) acc += dot4(X[lane + q * 64], W[lane + q * 64]);
    #pragma unroll
    for (int m = 1; m < 64; m <<= 1) acc += __shfl_xor(acc, m);
    if (lane == 0) xdbl[l * 64 + f] = acc;
}

// ---------------------------------------------------------------------------
// Kernel 5: dt[l,e] = softplus(dot(x_dbl[l,:32], Wdt[e,:32]) + bdt[e])
// ---------------------------------------------------------------------------
__global__ __launch_bounds__(256) void dtproj_k(const float* __restrict__ xdbl,
                                                const float* __restrict__ Wdt,
                                                const float* __restrict__ bdt,
                                                float* __restrict__ dt){
    int idx = blockIdx.x * 256 + threadIdx.x;   // 0..65535
    int l = idx >> 10;
    int e = idx & 1023;
    const float* r = xdbl + l * 64;
    const float* w = Wdt + e * 32;
    float acc = bdt[e];
    #pragma unroll
    for (int k = 0; k < 32; k++) acc += r[k] * w[k];
    float sp = (acc > 20.f) ? acc : log1pf(expf(acc));
    dt[l * 1024 + e] = sp;
}

// ---------------------------------------------------------------------------
// Kernel 6: selective scan + skip + gate.
// Thread per (e,s): e = idx>>4, s = idx&15 (16-lane groups within wave).
// h_l = exp(dt*A)*h_{l-1} + dt*xs*B_l ;  y = <h,C_l> + xs*D ; y *= silu(z)
// ---------------------------------------------------------------------------
__global__ __launch_bounds__(256) void scan_k(const float* __restrict__ dt,
                                              const float* __restrict__ xs,
                                              const float* __restrict__ xdbl,
                                              const float* __restrict__ xz,
                                              const float* __restrict__ A_log,
                                              const float* __restrict__ Dv,
                                              float* __restrict__ y){
    int idx = blockIdx.x * 256 + threadIdx.x;   // 0..16383
    int e = idx >> 4;
    int s = idx & 15;
    float A  = -expf(A_log[e * 16 + s]);
    float Dd = Dv[e];
    float h = 0.f;
    for (int l = 0; l < 64; l++){
        float dtv = dt[l * 1024 + e];
        float xv  = xs[l * 1024 + e];
        float bv  = xdbl[l * 64 + 32 + s];
        float cv  = xdbl[l * 64 + 48 + s];
        h = expf(dtv * A) * h + (dtv * xv) * bv;
        float p = h * cv;
        p += __shfl_xor(p, 1);
        p += __shfl_xor(p, 2);
        p += __shfl_xor(p, 4);
        p += __shfl_xor(p, 8);
        if (s == 0){
            float yv = p + xv * Dd;
            float zv = xz[l * 2048 + 1024 + e];
            yv *= zv / (1.f + expf(-zv));
            y[l * 1024 + e] = yv;
        }
    }
}

// ---------------------------------------------------------------------------
// Kernel 7: out[l,d] = dot(y[l,:1024], Wo[d,:1024])   (64 x 512)
// ---------------------------------------------------------------------------
__global__ __launch_bounds__(256) void outproj_k(const float* __restrict__ y,
                                                 const float* __restrict__ Wo,
                                                 float* __restrict__ out){
    int lane = threadIdx.x & 63;
    int wid  = blockIdx.x * 4 + (threadIdx.x >> 6);  // 0..32767
    int l = wid >> 9;
    int d = wid & 511;
    const float4* Y = (const float4*)(y)  + (size_t)l * 256;
    const float4* W = (const float4*)(Wo) + (size_t)d * 256;
    float acc = 0.f;
    #pragma unroll
    for (int q = 0; q < 4; q++) acc += dot4(Y[lane + q * 64], W[lane + q * 64]);
    #pragma unroll
    for (int m = 1; m < 64; m <<= 1) acc += __shfl_xor(acc, m);
    if (lane == 0) out[l * 512 + d] = acc;
}

// ---------------------------------------------------------------------------
extern "C" void kernel_launch(void* const* d_in, const int* in_sizes, int n_in,
                              void* d_out, int out_size, void* d_ws, size_t ws_size,
                              hipStream_t stream){
    const float* x          = (const float*)d_in[0];
    const float* in_proj_w  = (const float*)d_in[1];
    const float* conv_w     = (const float*)d_in[2];
    const float* conv_b     = (const float*)d_in[3];
    const float* x_proj_w   = (const float*)d_in[4];
    const float* dt_proj_w  = (const float*)d_in[5];
    const float* dt_proj_b  = (const float*)d_in[6];
    const float* A_log      = (const float*)d_in[7];
    const float* Dv         = (const float*)d_in[8];
    const float* out_proj_w = (const float*)d_in[9];
    float* out = (float*)d_out;

    float* ws   = (float*)d_ws;
    float* seq  = ws;            // 64*512   = 32768
    float* xz   = ws + 32768;    // 64*2048  = 131072  (xs0 = [:,:1024], z = [:,1024:])
    float* xs   = ws + 163840;   // 64*1024  = 65536
    float* xdbl = ws + 229376;   // 64*64    = 4096
    float* dt   = ws + 233472;   // 64*1024  = 65536
    float* y    = ws + 299008;   // 64*1024  = 65536

    hipLaunchKernelGGL(pool_k,    dim3(1024),  dim3(256), 0, stream, x, seq);
    hipLaunchKernelGGL(inproj_k,  dim3(32768), dim3(256), 0, stream, seq, in_proj_w, xz);
    hipLaunchKernelGGL(conv_k,    dim3(256),   dim3(256), 0, stream, xz, conv_w, conv_b, xs);
    hipLaunchKernelGGL(xproj_k,   dim3(1024),  dim3(256), 0, stream, xs, x_proj_w, xdbl);
    hipLaunchKernelGGL(dtproj_k,  dim3(256),   dim3(256), 0, stream, xdbl, dt_proj_w, dt_proj_b, dt);
    hipLaunchKernelGGL(scan_k,    dim3(64),    dim3(256), 0, stream, dt, xs, xdbl, xz, A_log, Dv, y);
    hipLaunchKernelGGL(outproj_k, dim3(8192),  dim3(256), 0, stream, y, out_proj_w, out);
}